// Round 1
// baseline (913.289 us; speedup 1.0000x reference)
//
#include <hip/hip_runtime.h>
#include <hip/hip_bf16.h>

#define NTOK 8192
#define DIM 1024
#define HID 2816
#define NE 8
#define NSLOT (NTOK*2)          // 16384 token-slots (top-2)
#define BM 128
#define BN 128
#define BK 32
#define MAXMT (NSLOT/BM + NE)   // 136 worst-case M-tiles
#define LDK (BK+8)              // padded LDS stride: 40 bf16 = 80 B (16B-aligned, bank-uniform)

typedef float f32x4 __attribute__((ext_vector_type(4)));
typedef __bf16 bf16x8 __attribute__((ext_vector_type(8)));

#define MFMA(a,b,c) __builtin_amdgcn_mfma_f32_16x16x32_bf16(a,b,c,0,0,0)

__device__ __forceinline__ void cvt_st8(__bf16* d, f32x4 a, f32x4 b){
  bf16x8 v;
  v[0]=(__bf16)a.x; v[1]=(__bf16)a.y; v[2]=(__bf16)a.z; v[3]=(__bf16)a.w;
  v[4]=(__bf16)b.x; v[5]=(__bf16)b.y; v[6]=(__bf16)b.z; v[7]=(__bf16)b.w;
  *reinterpret_cast<bf16x8*>(d) = v;
}

// ---------------- gating ----------------
__global__ void k_zero(int* cnt){ if(threadIdx.x < NE) cnt[threadIdx.x] = 0; }

__global__ __launch_bounds__(256) void k_gate(const float* __restrict__ x,
    const float* __restrict__ gw, int* __restrict__ idxs,
    float* __restrict__ wt, int* __restrict__ cnt)
{
  int lane = threadIdx.x & 63;
  int t = blockIdx.x*4 + (threadIdx.x >> 6);
  const f32x4* x4 = reinterpret_cast<const f32x4*>(x) + (size_t)t*(DIM/4);
  const f32x4* g4 = reinterpret_cast<const f32x4*>(gw);
  f32x4 xv[4];
#pragma unroll
  for(int i=0;i<4;i++) xv[i] = x4[i*64 + lane];
  double logit[NE];
#pragma unroll
  for(int e=0;e<NE;e++){
    double s = 0.0;
#pragma unroll
    for(int i=0;i<4;i++){
      f32x4 g = g4[e*(DIM/4) + i*64 + lane];
      s += (double)xv[i].x*g.x + (double)xv[i].y*g.y
         + (double)xv[i].z*g.z + (double)xv[i].w*g.w;
    }
#pragma unroll
    for(int d=32; d>0; d>>=1) s += __shfl_xor(s, d, 64);
    logit[e] = s;
  }
  if(lane==0){
    int i1=0; double m1=logit[0];
#pragma unroll
    for(int e=1;e<NE;e++) if(logit[e]>m1){ m1=logit[e]; i1=e; }
    int i2=-1; double m2=-1e300;
#pragma unroll
    for(int e=0;e<NE;e++) if(e!=i1 && logit[e]>m2){ m2=logit[e]; i2=e; }
    float e2 = __expf((float)(m2-m1));   // exp of (top2-top1) <= 0
    float w0 = 1.f/(1.f+e2);
    idxs[2*t]=i1; idxs[2*t+1]=i2;
    wt[2*t]=w0;   wt[2*t+1]=e2*w0;
    atomicAdd(&cnt[i1],1); atomicAdd(&cnt[i2],1);
  }
}

__global__ void k_prep(const int* __restrict__ cnt, int* __restrict__ off,
                       int* __restrict__ mtp, int* __restrict__ cursor)
{
  if(threadIdx.x==0){
    int o=0, m=0; off[0]=0; mtp[0]=0;
    for(int e=0;e<NE;e++){
      cursor[e]=o; o += cnt[e]; off[e+1]=o;
      m += (cnt[e]+BM-1)/BM;  mtp[e+1]=m;
    }
  }
}

__global__ __launch_bounds__(256) void k_scatter(const int* __restrict__ idxs,
    int* __restrict__ cursor, int* __restrict__ order, int* __restrict__ inv)
{
  int t = blockIdx.x*blockDim.x + threadIdx.x;
#pragma unroll
  for(int k=0;k<2;k++){
    int s = 2*t+k;
    int e = idxs[s];
    int p = atomicAdd(&cursor[e],1);
    order[p]=s; inv[s]=p;
  }
}

// ---------------- FFN stage 1: h = silu(x@w1^T) * (x@w3^T) ----------------
__global__ __launch_bounds__(512) void k_ffn1(
    const float* __restrict__ x, const float* __restrict__ w1,
    const float* __restrict__ w3, const int* __restrict__ off,
    const int* __restrict__ mtp, const int* __restrict__ order,
    __bf16* __restrict__ h)
{
  __shared__ __align__(16) __bf16 lA [2][BM][LDK];
  __shared__ __align__(16) __bf16 lB1[2][BN][LDK];
  __shared__ __align__(16) __bf16 lB3[2][BN][LDK];

  const int NT = HID/BN;                 // 22
  int mt = blockIdx.x / NT, nt = blockIdx.x % NT;
  if (mt >= mtp[NE]) return;
  int e = 0;
  while (mt >= mtp[e+1]) e++;
  int row0   = off[e] + (mt - mtp[e])*BM;
  int row_end= off[e+1];
  int n0     = nt*BN;

  int tid = threadIdx.x;
  int sr = tid>>2, sc = (tid&3)*8;       // staging: row, col0 (8 fp32)
  int p  = min(row0 + sr, row_end-1);
  int tok = order[p] >> 1;
  const float* gA  = x  + (size_t)tok*DIM + sc;
  const float* gB1 = w1 + (size_t)e*HID*DIM + (size_t)(n0+sr)*DIM + sc;
  const float* gB3 = w3 + (size_t)e*HID*DIM + (size_t)(n0+sr)*DIM + sc;

  int lane = tid & 63;
  int wm = (tid>>6)>>2, wn = (tid>>6)&3; // 2x4 wave grid, wave tile 64x32
  int fr = lane & 15, ko = (lane>>4)*8;

  f32x4 acc1[4][2], acc3[4][2];
#pragma unroll
  for(int m=0;m<4;m++)
#pragma unroll
    for(int n=0;n<2;n++){ acc1[m][n]=f32x4{0.f,0.f,0.f,0.f}; acc3[m][n]=f32x4{0.f,0.f,0.f,0.f}; }

  { // prologue: stage kt=0
    f32x4 a0=*(const f32x4*)gA,      a1=*(const f32x4*)(gA+4);
    f32x4 b0=*(const f32x4*)gB1,     b1=*(const f32x4*)(gB1+4);
    f32x4 c0=*(const f32x4*)gB3,     c1=*(const f32x4*)(gB3+4);
    cvt_st8(&lA [0][sr][sc],a0,a1);
    cvt_st8(&lB1[0][sr][sc],b0,b1);
    cvt_st8(&lB3[0][sr][sc],c0,c1);
  }
  __syncthreads();

  const int NK = DIM/BK;                 // 32
  int buf=0;
  for(int kt=0; kt<NK; kt++){
    f32x4 a0,a1,b0,b1,c0,c1;
    if(kt+1<NK){                         // issue next-tile loads before MFMA phase
      const float* pA=gA +(kt+1)*BK;
      const float* pB=gB1+(kt+1)*BK;
      const float* pC=gB3+(kt+1)*BK;
      a0=*(const f32x4*)pA; a1=*(const f32x4*)(pA+4);
      b0=*(const f32x4*)pB; b1=*(const f32x4*)(pB+4);
      c0=*(const f32x4*)pC; c1=*(const f32x4*)(pC+4);
    }
    bf16x8 av[4], bv[2], cv[2];
#pragma unroll
    for(int m=0;m<4;m++) av[m]=*reinterpret_cast<const bf16x8*>(&lA[buf][wm*64+m*16+fr][ko]);
#pragma unroll
    for(int n=0;n<2;n++){
      bv[n]=*reinterpret_cast<const bf16x8*>(&lB1[buf][wn*32+n*16+fr][ko]);
      cv[n]=*reinterpret_cast<const bf16x8*>(&lB3[buf][wn*32+n*16+fr][ko]);
    }
#pragma unroll
    for(int m=0;m<4;m++)
#pragma unroll
      for(int n=0;n<2;n++){
        acc1[m][n]=MFMA(av[m],bv[n],acc1[m][n]);
        acc3[m][n]=MFMA(av[m],cv[n],acc3[m][n]);
      }
    if(kt+1<NK){
      cvt_st8(&lA [buf^1][sr][sc],a0,a1);
      cvt_st8(&lB1[buf^1][sr][sc],b0,b1);
      cvt_st8(&lB3[buf^1][sr][sc],c0,c1);
    }
    __syncthreads();
    buf^=1;
  }

  // epilogue: h = silu(acc1)*acc3, masked at segment end (pad rows alias next expert!)
#pragma unroll
  for(int m=0;m<4;m++){
    int rbase = row0 + wm*64 + m*16 + ((lane>>4)<<2);
#pragma unroll
    for(int r=0;r<4;r++){
      if(rbase+r < row_end){
        __bf16* hp = h + (size_t)(rbase+r)*HID + n0 + wn*32 + fr;
#pragma unroll
        for(int n=0;n<2;n++){
          float u = acc1[m][n][r], v = acc3[m][n][r];
          hp[n*16] = (__bf16)( (u/(1.f+__expf(-u))) * v );
        }
      }
    }
  }
}

// ---------------- FFN stage 2: ys = h @ w2^T ----------------
__global__ __launch_bounds__(512) void k_ffn2(
    const __bf16* __restrict__ h, const float* __restrict__ w2,
    const int* __restrict__ off, const int* __restrict__ mtp,
    __bf16* __restrict__ ys)
{
  __shared__ __align__(16) __bf16 lA[2][BM][LDK];
  __shared__ __align__(16) __bf16 lB[2][BN][LDK];

  const int NT = DIM/BN;                 // 8
  int mt = blockIdx.x / NT, nt = blockIdx.x % NT;
  if (mt >= mtp[NE]) return;
  int e = 0;
  while (mt >= mtp[e+1]) e++;
  int row0   = off[e] + (mt - mtp[e])*BM;
  int row_end= off[e+1];
  int n0     = nt*BN;

  int tid = threadIdx.x;
  int sr = tid>>2, sc = (tid&3)*8;
  int hr = min(row0 + sr, NSLOT-1);      // clamp (tail tile may exceed NSLOT)
  const __bf16* gA = h  + (size_t)hr*HID + sc;
  const float*  gB = w2 + (size_t)e*DIM*HID + (size_t)(n0+sr)*HID + sc;

  int lane = tid & 63;
  int wm = (tid>>6)>>2, wn = (tid>>6)&3;
  int fr = lane & 15, ko = (lane>>4)*8;

  f32x4 acc[4][2];
#pragma unroll
  for(int m=0;m<4;m++)
#pragma unroll
    for(int n=0;n<2;n++) acc[m][n]=f32x4{0.f,0.f,0.f,0.f};

  {
    f32x4 ra = *(const f32x4*)gA;        // 8 bf16 raw copy (16B)
    f32x4 b0=*(const f32x4*)gB, b1=*(const f32x4*)(gB+4);
    *reinterpret_cast<f32x4*>(&lA[0][sr][sc]) = ra;
    cvt_st8(&lB[0][sr][sc],b0,b1);
  }
  __syncthreads();

  const int NK = HID/BK;                 // 88
  int buf=0;
  for(int kt=0; kt<NK; kt++){
    f32x4 ra,b0,b1;
    if(kt+1<NK){
      ra=*(const f32x4*)(gA+(kt+1)*BK);
      const float* pB=gB+(kt+1)*BK;
      b0=*(const f32x4*)pB; b1=*(const f32x4*)(pB+4);
    }
    bf16x8 av[4], bv[2];
#pragma unroll
    for(int m=0;m<4;m++) av[m]=*reinterpret_cast<const bf16x8*>(&lA[buf][wm*64+m*16+fr][ko]);
#pragma unroll
    for(int n=0;n<2;n++) bv[n]=*reinterpret_cast<const bf16x8*>(&lB[buf][wn*32+n*16+fr][ko]);
#pragma unroll
    for(int m=0;m<4;m++)
#pragma unroll
      for(int n=0;n<2;n++)
        acc[m][n]=MFMA(av[m],bv[n],acc[m][n]);
    if(kt+1<NK){
      *reinterpret_cast<f32x4*>(&lA[buf^1][sr][sc]) = ra;
      cvt_st8(&lB[buf^1][sr][sc],b0,b1);
    }
    __syncthreads();
    buf^=1;
  }

#pragma unroll
  for(int m=0;m<4;m++){
    int rbase = row0 + wm*64 + m*16 + ((lane>>4)<<2);
#pragma unroll
    for(int r=0;r<4;r++){
      if(rbase+r < row_end){
        __bf16* yp = ys + (size_t)(rbase+r)*DIM + n0 + wn*32 + fr;
#pragma unroll
        for(int n=0;n<2;n++) yp[n*16] = (__bf16)acc[m][n][r];
      }
    }
  }
}

// ---------------- weighted combine of the 2 slots ----------------
__global__ __launch_bounds__(256) void k_combine(
    const __bf16* __restrict__ ys, const int* __restrict__ inv,
    const float* __restrict__ wt, float* __restrict__ y)
{
  int t  = blockIdx.x;
  int p0 = inv[2*t], p1 = inv[2*t+1];
  float w0 = wt[2*t], w1v = wt[2*t+1];
  int d = threadIdx.x*4;
  const __bf16* r0 = ys + (size_t)p0*DIM + d;
  const __bf16* r1 = ys + (size_t)p1*DIM + d;
  f32x4 o;
#pragma unroll
  for(int j=0;j<4;j++) o[j] = w0*(float)r0[j] + w1v*(float)r1[j];
  *reinterpret_cast<f32x4*>(y + (size_t)t*DIM + d) = o;
}

// ---------------- launch ----------------
extern "C" void kernel_launch(void* const* d_in, const int* in_sizes, int n_in,
                              void* d_out, int out_size, void* d_ws, size_t ws_size,
                              hipStream_t stream)
{
  const float* x  = (const float*)d_in[0];
  const float* gw = (const float*)d_in[1];
  const float* w1 = (const float*)d_in[2];
  const float* w3 = (const float*)d_in[3];
  const float* w2 = (const float*)d_in[4];
  float* y = (float*)d_out;
  char* ws = (char*)d_ws;

  int*   cnt    = (int*)(ws + 0);
  int*   off    = (int*)(ws + 64);
  int*   mtp    = (int*)(ws + 128);
  int*   cursor = (int*)(ws + 192);
  int*   idxs   = (int*)(ws + 256);                    // 64 KB
  float* wt     = (float*)(ws + 256 + 65536);          // 64 KB
  int*   order  = (int*)(ws + 256 + 2*65536);          // 64 KB
  int*   inv    = (int*)(ws + 256 + 3*65536);          // 64 KB
  __bf16* h     = (__bf16*)(ws + 262400);              // 16384*2816*2 = 92,274,688 B
  __bf16* ysb   = (__bf16*)(ws + 262400 + 92274688);   // 16384*1024*2 = 33,554,432 B

  k_zero   <<<1, 64, 0, stream>>>(cnt);
  k_gate   <<<NTOK/4, 256, 0, stream>>>(x, gw, idxs, wt, cnt);
  k_prep   <<<1, 64, 0, stream>>>(cnt, off, mtp, cursor);
  k_scatter<<<NTOK/256, 256, 0, stream>>>(idxs, cursor, order, inv);
  k_ffn1   <<<MAXMT*(HID/BN), 512, 0, stream>>>(x, w1, w3, off, mtp, order, h);
  k_ffn2   <<<MAXMT*(DIM/BN), 512, 0, stream>>>(h, w2, off, mtp, ysb);
  k_combine<<<NTOK, 256, 0, stream>>>(ysb, inv, wt, y);
}

// Round 2
// 752.259 us; speedup vs baseline: 1.2141x; 1.2141x over previous
//
#include <hip/hip_runtime.h>
#include <hip/hip_bf16.h>

#define NTOK 8192
#define DIM 1024
#define HID 2816
#define NE 8
#define NSLOT (NTOK*2)          // 16384 token-slots (top-2)
#define BM 128
#define BN 128
#define BK 32
#define MAXMT (NSLOT/BM + NE)   // 136 worst-case M-tiles

typedef float f32x4 __attribute__((ext_vector_type(4)));
typedef __bf16 bf16x8 __attribute__((ext_vector_type(8)));
typedef __bf16 bf16x4 __attribute__((ext_vector_type(4)));

#define MFMA(a,b,c) __builtin_amdgcn_mfma_f32_16x16x32_bf16(a,b,c,0,0,0)

__device__ __forceinline__ void cvt_st8(__bf16* d, f32x4 a, f32x4 b){
  bf16x8 v;
  v[0]=(__bf16)a.x; v[1]=(__bf16)a.y; v[2]=(__bf16)a.z; v[3]=(__bf16)a.w;
  v[4]=(__bf16)b.x; v[5]=(__bf16)b.y; v[6]=(__bf16)b.z; v[7]=(__bf16)b.w;
  *reinterpret_cast<bf16x8*>(d) = v;
}

// async global->LDS, 16B per lane. LDS dest = wave-uniform base + lane*16.
__device__ __forceinline__ void gld_lds16(const void* g, void* l){
  __builtin_amdgcn_global_load_lds(
    (const __attribute__((address_space(1))) void*)g,
    (__attribute__((address_space(3))) void*)l, 16, 0, 0);
}

// XOR-swizzled element index in a linear [rows][BK] bf16 tile.
// granule (16B = 8 bf16) g' = g ^ ((row>>1)&3): 8 distinct bank-starts per
// 8 rows -> conflict-free ds_read_b128 column reads.
__device__ __forceinline__ int swz(int r, int g){ return r*BK + ((g ^ ((r>>1)&3))<<3); }

// bijective XCD-aware remap (m204): consecutive mapped ids land on one XCD
__device__ __forceinline__ int xcd_map(int orig, int nwg){
  int q = nwg>>3, rr = nwg&7, x = orig&7, o = orig>>3;
  return (x<rr ? x*(q+1) : rr*(q+1)+(x-rr)*q) + o;
}

// ---------------- small utility kernels ----------------
__global__ void k_zero(int* cnt){ if(threadIdx.x < NE) cnt[threadIdx.x] = 0; }

__global__ __launch_bounds__(256) void k_zero_y(float* __restrict__ y){
  int i = blockIdx.x*256 + threadIdx.x;
  reinterpret_cast<f32x4*>(y)[i] = f32x4{0.f,0.f,0.f,0.f};
}

__global__ __launch_bounds__(256) void k_cvt(const float* __restrict__ src,
                                             __bf16* __restrict__ dst){
  int i = blockIdx.x*256 + threadIdx.x;
  const f32x4* s = reinterpret_cast<const f32x4*>(src) + (size_t)i*2;
  f32x4 a = s[0], b = s[1];
  cvt_st8(dst + (size_t)i*8, a, b);
}

// ---------------- gating (also emits bf16 x) ----------------
__global__ __launch_bounds__(256) void k_gate(const float* __restrict__ x,
    const float* __restrict__ gw, int* __restrict__ idxs,
    float* __restrict__ wt, int* __restrict__ cnt, __bf16* __restrict__ xb)
{
  int lane = threadIdx.x & 63;
  int t = blockIdx.x*4 + (threadIdx.x >> 6);
  const f32x4* x4 = reinterpret_cast<const f32x4*>(x) + (size_t)t*(DIM/4);
  const f32x4* g4 = reinterpret_cast<const f32x4*>(gw);
  f32x4 xv[4];
#pragma unroll
  for(int i=0;i<4;i++) xv[i] = x4[i*64 + lane];
  double logit[NE];
#pragma unroll
  for(int e=0;e<NE;e++){
    double s = 0.0;
#pragma unroll
    for(int i=0;i<4;i++){
      f32x4 g = g4[e*(DIM/4) + i*64 + lane];
      s += (double)xv[i].x*g.x + (double)xv[i].y*g.y
         + (double)xv[i].z*g.z + (double)xv[i].w*g.w;
    }
#pragma unroll
    for(int d=32; d>0; d>>=1) s += __shfl_xor(s, d, 64);
    logit[e] = s;
  }
  // bf16 copy of x (same rounding as weights path)
  __bf16* xo = xb + (size_t)t*DIM;
#pragma unroll
  for(int i=0;i<4;i++){
    bf16x4 v;
    v[0]=(__bf16)xv[i].x; v[1]=(__bf16)xv[i].y;
    v[2]=(__bf16)xv[i].z; v[3]=(__bf16)xv[i].w;
    *reinterpret_cast<bf16x4*>(xo + (i*64+lane)*4) = v;
  }
  if(lane==0){
    int i1=0; double m1=logit[0];
#pragma unroll
    for(int e=1;e<NE;e++) if(logit[e]>m1){ m1=logit[e]; i1=e; }
    int i2=-1; double m2=-1e300;
#pragma unroll
    for(int e=0;e<NE;e++) if(e!=i1 && logit[e]>m2){ m2=logit[e]; i2=e; }
    float e2 = __expf((float)(m2-m1));
    float w0 = 1.f/(1.f+e2);
    idxs[2*t]=i1; idxs[2*t+1]=i2;
    wt[2*t]=w0;   wt[2*t+1]=e2*w0;
    atomicAdd(&cnt[i1],1); atomicAdd(&cnt[i2],1);
  }
}

__global__ void k_prep(const int* __restrict__ cnt, int* __restrict__ off,
                       int* __restrict__ mtp, int* __restrict__ cursor)
{
  if(threadIdx.x==0){
    int o=0, m=0; off[0]=0; mtp[0]=0;
    for(int e=0;e<NE;e++){
      cursor[e]=o; o += cnt[e]; off[e+1]=o;
      m += (cnt[e]+BM-1)/BM;  mtp[e+1]=m;
    }
  }
}

__global__ __launch_bounds__(256) void k_scatter(const int* __restrict__ idxs,
    int* __restrict__ cursor, int* __restrict__ order)
{
  int t = blockIdx.x*blockDim.x + threadIdx.x;
#pragma unroll
  for(int k=0;k<2;k++){
    int s = 2*t+k;
    int e = idxs[s];
    int p = atomicAdd(&cursor[e],1);
    order[p]=s;
  }
}

// ---------------- FFN stage 1: h = silu(x@w1^T) * (x@w3^T) ----------------
__global__ __launch_bounds__(512) void k_ffn1(
    const __bf16* __restrict__ xb, const __bf16* __restrict__ w1b,
    const __bf16* __restrict__ w3b, const int* __restrict__ off,
    const int* __restrict__ mtp, const int* __restrict__ order,
    __bf16* __restrict__ h)
{
  __shared__ __align__(16) __bf16 lA [2][BM*BK];
  __shared__ __align__(16) __bf16 lB1[2][BN*BK];
  __shared__ __align__(16) __bf16 lB3[2][BN*BK];

  const int NT = HID/BN;                 // 22
  int wg = xcd_map(blockIdx.x, MAXMT*NT);
  int mt = wg / NT, nt = wg % NT;
  if (mt >= mtp[NE]) return;
  int e = 0;
  while (mt >= mtp[e+1]) e++;
  int row0   = off[e] + (mt - mtp[e])*BM;
  int row_end= off[e+1];
  int n0     = nt*BN;

  int tid = threadIdx.x, lane = tid & 63;
  // staging: thread -> (row, granule); source granule pre-swizzled by row
  int srow = tid>>2;
  int scol = ((tid&3) ^ ((srow>>1)&3))<<3;
  int arow = min(row0 + srow, row_end-1);
  int tok  = order[arow] >> 1;
  const __bf16* gA  = xb  + (size_t)tok*DIM + scol;
  const __bf16* gB1 = w1b + (size_t)e*HID*DIM + (size_t)(n0+srow)*DIM + scol;
  const __bf16* gB3 = w3b + (size_t)e*HID*DIM + (size_t)(n0+srow)*DIM + scol;
  int ldso = (tid>>6)<<9;                // wave * 512 elements (1KB)

  int wm = (tid>>6)>>2, wn = (tid>>6)&3; // 2x4 wave grid, wave tile 64x32
  int fr = lane & 15, gq = lane>>4;

  f32x4 acc1[4][2], acc3[4][2];
#pragma unroll
  for(int m=0;m<4;m++)
#pragma unroll
    for(int n=0;n<2;n++){ acc1[m][n]=f32x4{0.f,0.f,0.f,0.f}; acc3[m][n]=f32x4{0.f,0.f,0.f,0.f}; }

  gld_lds16(gA,  &lA [0][ldso]);
  gld_lds16(gB1, &lB1[0][ldso]);
  gld_lds16(gB3, &lB3[0][ldso]);
  __syncthreads();

  const int NK = DIM/BK;                 // 32
  int buf=0;
  for(int kt=0; kt<NK; kt++){
    if(kt+1<NK){                         // issue next tile before compute
      gld_lds16(gA  + (kt+1)*BK, &lA [buf^1][ldso]);
      gld_lds16(gB1 + (kt+1)*BK, &lB1[buf^1][ldso]);
      gld_lds16(gB3 + (kt+1)*BK, &lB3[buf^1][ldso]);
    }
    bf16x8 av[4], bv[2], cv[2];
#pragma unroll
    for(int m=0;m<4;m++) av[m]=*reinterpret_cast<const bf16x8*>(&lA[buf][swz(wm*64+m*16+fr, gq)]);
#pragma unroll
    for(int n=0;n<2;n++){
      bv[n]=*reinterpret_cast<const bf16x8*>(&lB1[buf][swz(wn*32+n*16+fr, gq)]);
      cv[n]=*reinterpret_cast<const bf16x8*>(&lB3[buf][swz(wn*32+n*16+fr, gq)]);
    }
#pragma unroll
    for(int m=0;m<4;m++)
#pragma unroll
      for(int n=0;n<2;n++){
        acc1[m][n]=MFMA(av[m],bv[n],acc1[m][n]);
        acc3[m][n]=MFMA(av[m],cv[n],acc3[m][n]);
      }
    __syncthreads();
    buf^=1;
  }

  // epilogue: h = silu(acc1)*acc3, masked at segment end
#pragma unroll
  for(int m=0;m<4;m++){
    int rbase = row0 + wm*64 + m*16 + ((lane>>4)<<2);
#pragma unroll
    for(int r=0;r<4;r++){
      if(rbase+r < row_end){
        __bf16* hp = h + (size_t)(rbase+r)*HID + n0 + wn*32 + fr;
#pragma unroll
        for(int n=0;n<2;n++){
          float u = acc1[m][n][r], v = acc3[m][n][r];
          hp[n*16] = (__bf16)( (u/(1.f+__expf(-u))) * v );
        }
      }
    }
  }
}

// ---------------- FFN stage 2: y[t] += wt * (h @ w2^T) ----------------
__global__ __launch_bounds__(512) void k_ffn2(
    const __bf16* __restrict__ h, const __bf16* __restrict__ w2b,
    const int* __restrict__ off, const int* __restrict__ mtp,
    const int* __restrict__ order, const float* __restrict__ wt,
    float* __restrict__ y)
{
  __shared__ __align__(16) __bf16 lA[2][BM*BK];
  __shared__ __align__(16) __bf16 lB[2][BN*BK];

  const int NT = DIM/BN;                 // 8
  int wg = xcd_map(blockIdx.x, MAXMT*NT);
  int mt = wg / NT, nt = wg % NT;
  if (mt >= mtp[NE]) return;
  int e = 0;
  while (mt >= mtp[e+1]) e++;
  int row0   = off[e] + (mt - mtp[e])*BM;
  int row_end= off[e+1];
  int n0     = nt*BN;

  int tid = threadIdx.x, lane = tid & 63;
  int srow = tid>>2;
  int scol = ((tid&3) ^ ((srow>>1)&3))<<3;
  int hrow = min(row0 + srow, NSLOT-1);
  const __bf16* gA = h   + (size_t)hrow*HID + scol;
  const __bf16* gB = w2b + (size_t)e*DIM*HID + (size_t)(n0+srow)*HID + scol;
  int ldso = (tid>>6)<<9;

  int wm = (tid>>6)>>2, wn = (tid>>6)&3;
  int fr = lane & 15, gq = lane>>4;

  f32x4 acc[4][2];
#pragma unroll
  for(int m=0;m<4;m++)
#pragma unroll
    for(int n=0;n<2;n++) acc[m][n]=f32x4{0.f,0.f,0.f,0.f};

  gld_lds16(gA, &lA[0][ldso]);
  gld_lds16(gB, &lB[0][ldso]);
  __syncthreads();

  const int NK = HID/BK;                 // 88
  int buf=0;
  for(int kt=0; kt<NK; kt++){
    if(kt+1<NK){
      gld_lds16(gA + (kt+1)*BK, &lA[buf^1][ldso]);
      gld_lds16(gB + (kt+1)*BK, &lB[buf^1][ldso]);
    }
    bf16x8 av[4], bv[2];
#pragma unroll
    for(int m=0;m<4;m++) av[m]=*reinterpret_cast<const bf16x8*>(&lA[buf][swz(wm*64+m*16+fr, gq)]);
#pragma unroll
    for(int n=0;n<2;n++) bv[n]=*reinterpret_cast<const bf16x8*>(&lB[buf][swz(wn*32+n*16+fr, gq)]);
#pragma unroll
    for(int m=0;m<4;m++)
#pragma unroll
      for(int n=0;n<2;n++)
        acc[m][n]=MFMA(av[m],bv[n],acc[m][n]);
    __syncthreads();
    buf^=1;
  }

  // epilogue: weighted atomic combine (2 commutative addends per y element)
#pragma unroll
  for(int m=0;m<4;m++){
    int rbase = row0 + wm*64 + m*16 + ((lane>>4)<<2);
#pragma unroll
    for(int r=0;r<4;r++){
      int p = rbase + r;
      if(p < row_end){
        int s = order[p];
        float wv = wt[s];
        float* yp = y + (size_t)(s>>1)*DIM + n0 + wn*32 + fr;
        atomicAdd(&yp[0],  wv*acc[m][0][r]);
        atomicAdd(&yp[16], wv*acc[m][1][r]);
      }
    }
  }
}

// ---------------- launch ----------------
extern "C" void kernel_launch(void* const* d_in, const int* in_sizes, int n_in,
                              void* d_out, int out_size, void* d_ws, size_t ws_size,
                              hipStream_t stream)
{
  const float* x  = (const float*)d_in[0];
  const float* gw = (const float*)d_in[1];
  const float* w1 = (const float*)d_in[2];
  const float* w3 = (const float*)d_in[3];
  const float* w2 = (const float*)d_in[4];
  float* y = (float*)d_out;
  char* ws = (char*)d_ws;

  int*   cnt    = (int*)(ws + 0);
  int*   off    = (int*)(ws + 64);
  int*   mtp    = (int*)(ws + 128);
  int*   cursor = (int*)(ws + 192);
  int*   idxs   = (int*)(ws + 256);                    // 64 KB
  float* wt     = (float*)(ws + 65792);                // 64 KB
  int*   order  = (int*)(ws + 131328);                 // 64 KB
  __bf16* h     = (__bf16*)(ws + 262400);              // 16384*2816*2 = 92,274,688
  __bf16* xb    = (__bf16*)(ws + 262400 + 92274688ull);            // 16 MB
  __bf16* w1b   = (__bf16*)(ws + 262400 + 92274688ull + 16777216); // 44 MB
  __bf16* w3b   = (__bf16*)(ws + 262400 + 92274688ull + 16777216 + 46137344ull);
  __bf16* w2b   = (__bf16*)(ws + 262400 + 92274688ull + 16777216 + 2*46137344ull);
  // total = 247,726,336 B

  const int WN8 = NE*HID*DIM/8;          // 2,883,584 per weight tensor

  k_zero   <<<1, 64, 0, stream>>>(cnt);
  k_gate   <<<NTOK/4, 256, 0, stream>>>(x, gw, idxs, wt, cnt, xb);
  k_prep   <<<1, 64, 0, stream>>>(cnt, off, mtp, cursor);
  k_scatter<<<NTOK/256, 256, 0, stream>>>(idxs, cursor, order);
  k_cvt    <<<WN8/256, 256, 0, stream>>>(w1, w1b);
  k_cvt    <<<WN8/256, 256, 0, stream>>>(w3, w3b);
  k_cvt    <<<WN8/256, 256, 0, stream>>>(w2, w2b);
  k_zero_y <<<NTOK*DIM/4/256, 256, 0, stream>>>(y);
  k_ffn1   <<<MAXMT*(HID/BN), 512, 0, stream>>>(xb, w1b, w3b, off, mtp, order, h);
  k_ffn2   <<<MAXMT*(DIM/BN), 512, 0, stream>>>(h, w2b, off, mtp, order, wt, y);
}